// Round 3
// baseline (376.310 us; speedup 1.0000x reference)
//
#include <hip/hip_runtime.h>
#include <hip/hip_bf16.h>
#include <hip/hip_cooperative_groups.h>

namespace cg = cooperative_groups;

namespace {

constexpr int kB = 2;
constexpr int kL = 2048;
constexpr int kD = 1024;
constexpr int kN = 16;
constexpr int kTPB = 256;
constexpr int kNDBLK = kD / kTPB;   // 4 blocks cover D
constexpr int kBD = kB * kD;        // 2048
constexpr int kBDN = kBD * kN;      // 32768
constexpr float kLog2e = 1.4426950408889634f;

__device__ __forceinline__ float ex2(float v) {
  return __builtin_amdgcn_exp2f(v);
}

// a[n] = e1^(n+1), log-depth (4 squares + 11 muls)
__device__ __forceinline__ void build_pows(float e1, float* a) {
  const float p2 = e1 * e1;
  const float p4 = p2 * p2;
  const float p8 = p4 * p4;
  a[0] = e1;      a[1] = p2;      a[2] = p2 * e1;  a[3] = p4;
  a[4] = p4 * e1; a[5] = p4 * p2; a[6] = p4 * a[2]; a[7] = p8;
  a[8] = p8 * e1; a[9] = p8 * p2; a[10] = p8 * a[2]; a[11] = p8 * p4;
  a[12] = p8 * a[4]; a[13] = p8 * a[5]; a[14] = p8 * a[6]; a[15] = p8 * p8;
}

// =================== Fused cooperative kernel (C = 128) ===================
// Block (c, dblk, b): local chunk scan with x/dt held in REGISTERS,
// grid-sync, cross-chunk scan spread over all blocks, grid-sync,
// replay-from-registers with true init + fused epilogue.
template <int C>
__global__ __launch_bounds__(kTPB, 4) void ssm_coop(
    const float* __restrict__ x, const float* __restrict__ dt,
    const float* __restrict__ Bin, const float* __restrict__ Cin,
    const float* __restrict__ Alog, const float* __restrict__ Dp,
    float* __restrict__ WS, float* __restrict__ SDT,
    float* __restrict__ WI, float* __restrict__ y) {
  constexpr int LC = kL / C;  // 16
  static_assert(LC * kN == kTPB, "stage mapping");
  const int bid = blockIdx.x;
  const int c = bid % C;
  const int r = bid / C;
  const int dblk = r % kNDBLK;
  const int b = r / kNDBLK;
  const int tid = threadIdx.x;
  const int d = dblk * kTPB + tid;

  __shared__ float Bs[LC * kN];
  __shared__ float Cs[LC * kN];
  {
    const size_t src = ((size_t)b * kL + (size_t)c * LC) * kN + tid;
    Bs[tid] = Bin[src];
    Cs[tid] = Cin[src];
  }

  float AnL[kN];
  const float* al = Alog + d * kN;
#pragma unroll
  for (int n = 0; n < kN; ++n) AnL[n] = -__expf(al[n]) * kLog2e;
  bool fast = true;
#pragma unroll
  for (int n = 1; n < kN; ++n)
    fast = fast && (fabsf(AnL[n] - (float)(n + 1) * AnL[0]) <=
                    1e-4f * fabsf(AnL[n]));
  fast = __all(fast);

  __syncthreads();

  const float* xp = x + ((size_t)b * kL + (size_t)c * LC) * kD + d;
  const float* dp = dt + ((size_t)b * kL + (size_t)c * LC) * kD + d;

  float dtv[LC], xv[LC];
#pragma unroll
  for (int tt = 0; tt < LC; ++tt) {
    dtv[tt] = dp[(size_t)tt * kD];
    xv[tt] = xp[(size_t)tt * kD];
  }

  float s[kN];
#pragma unroll
  for (int n = 0; n < kN; ++n) s[n] = 0.f;
  float sdt = 0.f;

  if (fast) {
    const float A0 = AnL[0];
#pragma unroll
    for (int tt = 0; tt < LC; ++tt) {
      sdt += dtv[tt];
      const float dtx = dtv[tt] * xv[tt];
      float a[kN];
      build_pows(ex2(dtv[tt] * A0), a);
#pragma unroll
      for (int n = 0; n < kN; ++n)
        s[n] = fmaf(a[n], s[n], dtx * Bs[tt * kN + n]);
    }
  } else {
#pragma unroll 2
    for (int tt = 0; tt < LC; ++tt) {
      sdt += dtv[tt];
      const float dtx = dtv[tt] * xv[tt];
#pragma unroll
      for (int n = 0; n < kN; ++n)
        s[n] = fmaf(ex2(dtv[tt] * AnL[n]), s[n], dtx * Bs[tt * kN + n]);
    }
  }

  const size_t bd = (size_t)b * kD + d;
#pragma unroll
  for (int n = 0; n < kN; ++n)
    WS[(size_t)c * kBDN + (size_t)n * kBD + bd] = s[n];
  SDT[(size_t)c * kBD + bd] = sdt;

  cg::this_grid().sync();

  // ---- cross-chunk scan: 32 sequences per block, all blocks participate ----
  if (tid < 32) {
    const int seq = bid * 32 + tid;          // grid must be kBDN/32 blocks
    const int n = seq >> 11;                 // / kBD
    const int sbd = seq & (kBD - 1);
    const int sd = sbd & (kD - 1);
    const float An = -__expf(Alog[sd * kN + n]) * kLog2e;
    float carry = 0.f;
    for (int cc = 0; cc < C; ++cc) {
      const size_t idx = (size_t)cc * kBDN + seq;
      const float a = ex2(An * SDT[(size_t)cc * kBD + sbd]);
      WI[idx] = carry;                       // true initial state of chunk cc
      carry = fmaf(a, carry, WS[idx]);
    }
  }

  cg::this_grid().sync();

  // ---- replay from registers with true initial state, fused epilogue ----
#pragma unroll
  for (int n = 0; n < kN; ++n)
    s[n] = WI[(size_t)c * kBDN + (size_t)n * kBD + bd];

  const float Dv = Dp[d];
  float* yp = y + ((size_t)b * kL + (size_t)c * LC) * kD + d;

  if (fast) {
    const float A0 = AnL[0];
#pragma unroll
    for (int tt = 0; tt < LC; ++tt) {
      const float dtx = dtv[tt] * xv[tt];
      float a[kN];
      build_pows(ex2(dtv[tt] * A0), a);
      float acc = 0.f;
#pragma unroll
      for (int n = 0; n < kN; ++n) {
        s[n] = fmaf(a[n], s[n], dtx * Bs[tt * kN + n]);
        acc = fmaf(s[n], Cs[tt * kN + n], acc);
      }
      yp[(size_t)tt * kD] = fmaf(xv[tt], Dv, acc);
    }
  } else {
#pragma unroll 2
    for (int tt = 0; tt < LC; ++tt) {
      const float dtx = dtv[tt] * xv[tt];
      float acc = 0.f;
#pragma unroll
      for (int n = 0; n < kN; ++n) {
        s[n] = fmaf(ex2(dtv[tt] * AnL[n]), s[n], dtx * Bs[tt * kN + n]);
        acc = fmaf(s[n], Cs[tt * kN + n], acc);
      }
      yp[(size_t)tt * kD] = fmaf(xv[tt], Dv, acc);
    }
  }
}

// =================== Fallback: 3-kernel path ===================
template <int C>
__global__ __launch_bounds__(kTPB) void ssm_phase1(
    const float* __restrict__ x, const float* __restrict__ dt,
    const float* __restrict__ Bin, const float* __restrict__ Alog,
    float* __restrict__ WS, float* __restrict__ SDT) {
  constexpr int LC = kL / C;
  const int bid = blockIdx.x;
  const int c = bid % C;
  const int r = bid / C;
  const int dblk = r % kNDBLK;
  const int b = r / kNDBLK;
  const int d = dblk * kTPB + threadIdx.x;

  float AnL[kN];
  const float* al = Alog + d * kN;
#pragma unroll
  for (int n = 0; n < kN; ++n) AnL[n] = -__expf(al[n]) * kLog2e;
  bool fast = true;
#pragma unroll
  for (int n = 1; n < kN; ++n)
    fast = fast && (fabsf(AnL[n] - (float)(n + 1) * AnL[0]) <=
                    1e-4f * fabsf(AnL[n]));

  float s[kN];
#pragma unroll
  for (int n = 0; n < kN; ++n) s[n] = 0.f;
  float sdt = 0.f;

  const int t0 = c * LC;
  const float* xp = x + ((size_t)b * kL + t0) * kD + d;
  const float* dp = dt + ((size_t)b * kL + t0) * kD + d;
  const float* bp = Bin + ((size_t)b * kL + t0) * kN;

  if (fast) {
    const float A0 = AnL[0];
#pragma unroll 4
    for (int tt = 0; tt < LC; ++tt) {
      const float dtvv = dp[(size_t)tt * kD];
      const float xvv = xp[(size_t)tt * kD];
      sdt += dtvv;
      const float dtx = dtvv * xvv;
      float a[kN];
      build_pows(ex2(dtvv * A0), a);
#pragma unroll
      for (int n = 0; n < kN; ++n)
        s[n] = fmaf(a[n], s[n], dtx * bp[tt * kN + n]);
    }
  } else {
#pragma unroll 2
    for (int tt = 0; tt < LC; ++tt) {
      const float dtvv = dp[(size_t)tt * kD];
      const float xvv = xp[(size_t)tt * kD];
      sdt += dtvv;
      const float dtx = dtvv * xvv;
#pragma unroll
      for (int n = 0; n < kN; ++n)
        s[n] = fmaf(ex2(dtvv * AnL[n]), s[n], dtx * bp[tt * kN + n]);
    }
  }

  const size_t bd = (size_t)b * kD + d;
#pragma unroll
  for (int n = 0; n < kN; ++n)
    WS[(size_t)c * kBDN + (size_t)n * kBD + bd] = s[n];
  SDT[(size_t)c * kBD + bd] = sdt;
}

template <int C>
__global__ __launch_bounds__(256) void ssm_phase2(
    const float* __restrict__ WS, const float* __restrict__ SDT,
    const float* __restrict__ Alog, float* __restrict__ WI) {
  const int i = blockIdx.x * 256 + threadIdx.x;
  const int bd = i & (kBD - 1);
  const int d = bd & (kD - 1);
  const int n = i >> 11;
  const float An = -__expf(Alog[d * kN + n]) * kLog2e;
  float carry = 0.f;
  for (int c = 0; c < C; ++c) {
    const size_t idx = (size_t)c * kBDN + i;
    const float a = ex2(An * SDT[(size_t)c * kBD + bd]);
    WI[idx] = carry;
    carry = fmaf(a, carry, WS[idx]);
  }
}

template <int C>
__global__ __launch_bounds__(kTPB) void ssm_phase3(
    const float* __restrict__ x, const float* __restrict__ dt,
    const float* __restrict__ Bin, const float* __restrict__ Cin,
    const float* __restrict__ Alog, const float* __restrict__ Dp,
    const float* __restrict__ WI, float* __restrict__ y) {
  constexpr int LC = kL / C;
  const int bid = blockIdx.x;
  const int c = bid % C;
  const int r = bid / C;
  const int dblk = r % kNDBLK;
  const int b = r / kNDBLK;
  const int d = dblk * kTPB + threadIdx.x;

  float AnL[kN];
  const float* al = Alog + d * kN;
#pragma unroll
  for (int n = 0; n < kN; ++n) AnL[n] = -__expf(al[n]) * kLog2e;
  bool fast = true;
#pragma unroll
  for (int n = 1; n < kN; ++n)
    fast = fast && (fabsf(AnL[n] - (float)(n + 1) * AnL[0]) <=
                    1e-4f * fabsf(AnL[n]));

  float s[kN];
  const size_t bd = (size_t)b * kD + d;
#pragma unroll
  for (int n = 0; n < kN; ++n)
    s[n] = WI[(size_t)c * kBDN + (size_t)n * kBD + bd];

  const float Dv = Dp[d];
  const int t0 = c * LC;
  const float* xp = x + ((size_t)b * kL + t0) * kD + d;
  const float* dp = dt + ((size_t)b * kL + t0) * kD + d;
  const float* bp = Bin + ((size_t)b * kL + t0) * kN;
  const float* cp = Cin + ((size_t)b * kL + t0) * kN;
  float* yp = y + ((size_t)b * kL + t0) * kD + d;

  if (fast) {
    const float A0 = AnL[0];
#pragma unroll 4
    for (int tt = 0; tt < LC; ++tt) {
      const float dtvv = dp[(size_t)tt * kD];
      const float xvv = xp[(size_t)tt * kD];
      const float dtx = dtvv * xvv;
      float a[kN];
      build_pows(ex2(dtvv * A0), a);
      float acc = 0.f;
#pragma unroll
      for (int n = 0; n < kN; ++n) {
        s[n] = fmaf(a[n], s[n], dtx * bp[tt * kN + n]);
        acc = fmaf(s[n], cp[tt * kN + n], acc);
      }
      yp[(size_t)tt * kD] = fmaf(xvv, Dv, acc);
    }
  } else {
#pragma unroll 2
    for (int tt = 0; tt < LC; ++tt) {
      const float dtvv = dp[(size_t)tt * kD];
      const float xvv = xp[(size_t)tt * kD];
      const float dtx = dtvv * xvv;
      float acc = 0.f;
#pragma unroll
      for (int n = 0; n < kN; ++n) {
        s[n] = fmaf(ex2(dtvv * AnL[n]), s[n], dtx * bp[tt * kN + n]);
        acc = fmaf(s[n], cp[tt * kN + n], acc);
      }
      yp[(size_t)tt * kD] = fmaf(xvv, Dv, acc);
    }
  }
}

__global__ __launch_bounds__(256) void ssm_seq(
    const float* __restrict__ x, const float* __restrict__ dt,
    const float* __restrict__ Bin, const float* __restrict__ Cin,
    const float* __restrict__ Alog, const float* __restrict__ Dp,
    float* __restrict__ y) {
  const int gid = blockIdx.x * 256 + threadIdx.x;
  if (gid >= kB * kD) return;
  const int b = gid / kD;
  const int d = gid % kD;

  float AnL[kN];
  const float* al = Alog + d * kN;
#pragma unroll
  for (int n = 0; n < kN; ++n) AnL[n] = -__expf(al[n]) * kLog2e;

  float s[kN];
#pragma unroll
  for (int n = 0; n < kN; ++n) s[n] = 0.f;
  const float Dv = Dp[d];

  const float* xp = x + (size_t)b * kL * kD + d;
  const float* dp = dt + (size_t)b * kL * kD + d;
  const float* bp = Bin + (size_t)b * kL * kN;
  const float* cp = Cin + (size_t)b * kL * kN;
  float* yp = y + (size_t)b * kL * kD + d;

  for (int t = 0; t < kL; ++t) {
    const float dtvv = dp[(size_t)t * kD];
    const float xvv = xp[(size_t)t * kD];
    const float dtx = dtvv * xvv;
    float acc = 0.f;
#pragma unroll
    for (int n = 0; n < kN; ++n) {
      const float a = ex2(dtvv * AnL[n]);
      s[n] = fmaf(a, s[n], dtx * bp[t * kN + n]);
      acc = fmaf(s[n], cp[t * kN + n], acc);
    }
    yp[(size_t)t * kD] = fmaf(xvv, Dv, acc);
  }
}

template <int C>
void launch_chunked(const float* x, const float* dtp, const float* Bin,
                    const float* Cin, const float* Alog, const float* Dp,
                    float* y, float* ws, hipStream_t stream) {
  float* WS = ws;
  float* SDT = WS + (size_t)C * kBDN;
  float* WI = SDT + (size_t)C * kBD;
  const int g = C * kB * kNDBLK;
  ssm_phase1<C><<<g, kTPB, 0, stream>>>(x, dtp, Bin, Alog, WS, SDT);
  ssm_phase2<C><<<kBDN / 256, 256, 0, stream>>>(WS, SDT, Alog, WI);
  ssm_phase3<C><<<g, kTPB, 0, stream>>>(x, dtp, Bin, Cin, Alog, Dp, WI, y);
}

}  // namespace

extern "C" void kernel_launch(void* const* d_in, const int* in_sizes, int n_in,
                              void* d_out, int out_size, void* d_ws, size_t ws_size,
                              hipStream_t stream) {
  const float* x    = (const float*)d_in[0];
  const float* dtp  = (const float*)d_in[1];
  const float* Bin  = (const float*)d_in[2];
  const float* Cin  = (const float*)d_in[3];
  const float* Alog = (const float*)d_in[4];
  const float* Dp   = (const float*)d_in[5];
  float* y = (float*)d_out;
  float* ws = (float*)d_ws;

  auto need = [](int C) {
    return (size_t)(2 * C * kBDN + C * kBD) * sizeof(float);
  };

  if (ws_size >= need(128)) {
    constexpr int C = 128;
    float* WS = ws;
    float* SDT = WS + (size_t)C * kBDN;
    float* WI = SDT + (size_t)C * kBD;
    void* args[] = {(void*)&x,    (void*)&dtp, (void*)&Bin, (void*)&Cin,
                    (void*)&Alog, (void*)&Dp,  (void*)&WS,  (void*)&SDT,
                    (void*)&WI,   (void*)&y};
    const int grid = C * kB * kNDBLK;  // 1024 == kBDN/32
    hipError_t e = hipLaunchCooperativeKernel(
        reinterpret_cast<const void*>(&ssm_coop<C>), dim3(grid), dim3(kTPB),
        args, 0, stream);
    if (e != hipSuccess) {
      launch_chunked<C>(x, dtp, Bin, Cin, Alog, Dp, y, ws, stream);
    }
  } else if (ws_size >= need(64)) {
    launch_chunked<64>(x, dtp, Bin, Cin, Alog, Dp, y, ws, stream);
  } else if (ws_size >= need(16)) {
    launch_chunked<16>(x, dtp, Bin, Cin, Alog, Dp, y, ws, stream);
  } else {
    ssm_seq<<<(kB * kD + 255) / 256, 256, 0, stream>>>(x, dtp, Bin, Cin, Alog,
                                                       Dp, y);
  }
}

// Round 4
// 47.069 us; speedup vs baseline: 7.9948x; 7.9948x over previous
//
#include <hip/hip_runtime.h>
#include <hip/hip_bf16.h>

namespace {

constexpr int kB = 2;
constexpr int kL = 2048;
constexpr int kD = 1024;
constexpr int kN = 16;
constexpr int kTPB = 256;
constexpr int kNDBLK = kD / kTPB;   // 4 blocks cover D
constexpr int kBD = kB * kD;        // 2048
constexpr int kBDN = kBD * kN;      // 32768
constexpr float kLog2e = 1.4426950408889634f;

__device__ __forceinline__ float ex2(float v) {
  return __builtin_amdgcn_exp2f(v);
}

// a[n] = e1^(n+1), log-depth (4 squares + 11 muls)
__device__ __forceinline__ void build_pows(float e1, float* a) {
  const float p2 = e1 * e1;
  const float p4 = p2 * p2;
  const float p8 = p4 * p4;
  a[0] = e1;      a[1] = p2;      a[2] = p2 * e1;  a[3] = p4;
  a[4] = p4 * e1; a[5] = p4 * p2; a[6] = p4 * a[2]; a[7] = p8;
  a[8] = p8 * e1; a[9] = p8 * p2; a[10] = p8 * a[2]; a[11] = p8 * p4;
  a[12] = p8 * a[4]; a[13] = p8 * a[5]; a[14] = p8 * a[6]; a[15] = p8 * p8;
}

// Workspace layout (all [c][bd][n] / [c][bd]):
//   WS[(c*kBD + bd)*kN + n]  chunk-local final states (vector r/w)
//   SDT[c*kBD + bd]          chunk dt-sum
//   WI[(c*kBD + bd)*kN + n]  true initial state of chunk (vector r/w)

// ---------------- Phase 1: per-chunk local scan ----------------
template <int C>
__global__ __launch_bounds__(kTPB) void ssm_phase1(
    const float* __restrict__ x, const float* __restrict__ dt,
    const float* __restrict__ Bin, const float* __restrict__ Alog,
    float* __restrict__ WS, float* __restrict__ SDT) {
  constexpr int LC = kL / C;
  const int bid = blockIdx.x;
  const int c = bid % C;
  const int r = bid / C;
  const int dblk = r % kNDBLK;
  const int b = r / kNDBLK;
  const int tid = threadIdx.x;
  const int d = dblk * kTPB + tid;
  const int t0 = c * LC;

  __shared__ float Bs[LC * kN];
  for (int j = tid; j < LC * kN; j += kTPB)
    Bs[j] = Bin[((size_t)b * kL + t0) * kN + j];

  float AnL[kN];
  {
    const float4* alv = reinterpret_cast<const float4*>(Alog + (size_t)d * kN);
#pragma unroll
    for (int q = 0; q < 4; ++q) {
      const float4 v = alv[q];
      AnL[4 * q + 0] = -__expf(v.x) * kLog2e;
      AnL[4 * q + 1] = -__expf(v.y) * kLog2e;
      AnL[4 * q + 2] = -__expf(v.z) * kLog2e;
      AnL[4 * q + 3] = -__expf(v.w) * kLog2e;
    }
  }
  bool fast = true;
#pragma unroll
  for (int n = 1; n < kN; ++n)
    fast = fast && (fabsf(AnL[n] - (float)(n + 1) * AnL[0]) <=
                    1e-4f * fabsf(AnL[n]));

  __syncthreads();

  float s[kN];
#pragma unroll
  for (int n = 0; n < kN; ++n) s[n] = 0.f;
  float sdt = 0.f;

  const float* xp = x + ((size_t)b * kL + t0) * kD + d;
  const float* dp = dt + ((size_t)b * kL + t0) * kD + d;

  if (fast) {
    const float A0 = AnL[0];
#pragma unroll 4
    for (int tt = 0; tt < LC; ++tt) {
      const float dtv = dp[(size_t)tt * kD];
      const float xv = xp[(size_t)tt * kD];
      sdt += dtv;
      const float dtx = dtv * xv;
      float a[kN];
      build_pows(ex2(dtv * A0), a);
#pragma unroll
      for (int n = 0; n < kN; ++n)
        s[n] = fmaf(a[n], s[n], dtx * Bs[tt * kN + n]);
    }
  } else {
#pragma unroll 2
    for (int tt = 0; tt < LC; ++tt) {
      const float dtv = dp[(size_t)tt * kD];
      const float xv = xp[(size_t)tt * kD];
      sdt += dtv;
      const float dtx = dtv * xv;
#pragma unroll
      for (int n = 0; n < kN; ++n)
        s[n] = fmaf(ex2(dtv * AnL[n]), s[n], dtx * Bs[tt * kN + n]);
    }
  }

  const size_t bd = (size_t)b * kD + d;
  float4* wsv = reinterpret_cast<float4*>(WS + ((size_t)c * kBD + bd) * kN);
#pragma unroll
  for (int q = 0; q < 4; ++q)
    wsv[q] = make_float4(s[4 * q], s[4 * q + 1], s[4 * q + 2], s[4 * q + 3]);
  SDT[(size_t)c * kBD + bd] = sdt;
}

// ---------------- Phase 2: scan across chunk aggregates ----------------
template <int C>
__global__ __launch_bounds__(128) void ssm_phase2(
    const float* __restrict__ WS, const float* __restrict__ SDT,
    const float* __restrict__ Alog, float* __restrict__ WI) {
  const int i = blockIdx.x * 128 + threadIdx.x;  // < kBDN
  const int bd = i >> 4;        // sequence's (b,d)
  const int n = i & 15;
  const int d = bd & (kD - 1);
  const float An = -__expf(Alog[(size_t)d * kN + n]) * kLog2e;
  float carry = 0.f;
#pragma unroll 8
  for (int c = 0; c < C; ++c) {
    const size_t idx = ((size_t)c * kBD + bd) * kN + n;
    const float a = ex2(An * SDT[(size_t)c * kBD + bd]);
    WI[idx] = carry;
    carry = fmaf(a, carry, WS[idx]);
  }
}

// ---------------- Phase 3: replay with true init, fused epilogue ----------------
template <int C>
__global__ __launch_bounds__(kTPB) void ssm_phase3(
    const float* __restrict__ x, const float* __restrict__ dt,
    const float* __restrict__ Bin, const float* __restrict__ Cin,
    const float* __restrict__ Alog, const float* __restrict__ Dp,
    const float* __restrict__ WI, float* __restrict__ y) {
  constexpr int LC = kL / C;
  const int bid = blockIdx.x;
  const int c = bid % C;
  const int r = bid / C;
  const int dblk = r % kNDBLK;
  const int b = r / kNDBLK;
  const int tid = threadIdx.x;
  const int d = dblk * kTPB + tid;
  const int t0 = c * LC;

  __shared__ float Bs[LC * kN];
  __shared__ float Cs[LC * kN];
  for (int j = tid; j < LC * kN; j += kTPB) {
    Bs[j] = Bin[((size_t)b * kL + t0) * kN + j];
    Cs[j] = Cin[((size_t)b * kL + t0) * kN + j];
  }

  float AnL[kN];
  {
    const float4* alv = reinterpret_cast<const float4*>(Alog + (size_t)d * kN);
#pragma unroll
    for (int q = 0; q < 4; ++q) {
      const float4 v = alv[q];
      AnL[4 * q + 0] = -__expf(v.x) * kLog2e;
      AnL[4 * q + 1] = -__expf(v.y) * kLog2e;
      AnL[4 * q + 2] = -__expf(v.z) * kLog2e;
      AnL[4 * q + 3] = -__expf(v.w) * kLog2e;
    }
  }
  bool fast = true;
#pragma unroll
  for (int n = 1; n < kN; ++n)
    fast = fast && (fabsf(AnL[n] - (float)(n + 1) * AnL[0]) <=
                    1e-4f * fabsf(AnL[n]));

  __syncthreads();

  float s[kN];
  const size_t bd = (size_t)b * kD + d;
  {
    const float4* wiv =
        reinterpret_cast<const float4*>(WI + ((size_t)c * kBD + bd) * kN);
#pragma unroll
    for (int q = 0; q < 4; ++q) {
      const float4 v = wiv[q];
      s[4 * q + 0] = v.x;
      s[4 * q + 1] = v.y;
      s[4 * q + 2] = v.z;
      s[4 * q + 3] = v.w;
    }
  }

  const float Dv = Dp[d];
  const float* xp = x + ((size_t)b * kL + t0) * kD + d;
  const float* dp = dt + ((size_t)b * kL + t0) * kD + d;
  float* yp = y + ((size_t)b * kL + t0) * kD + d;

  if (fast) {
    const float A0 = AnL[0];
#pragma unroll 4
    for (int tt = 0; tt < LC; ++tt) {
      const float dtv = dp[(size_t)tt * kD];
      const float xv = xp[(size_t)tt * kD];
      const float dtx = dtv * xv;
      float a[kN];
      build_pows(ex2(dtv * A0), a);
      float acc = 0.f;
#pragma unroll
      for (int n = 0; n < kN; ++n) {
        s[n] = fmaf(a[n], s[n], dtx * Bs[tt * kN + n]);
        acc = fmaf(s[n], Cs[tt * kN + n], acc);
      }
      yp[(size_t)tt * kD] = fmaf(xv, Dv, acc);
    }
  } else {
#pragma unroll 2
    for (int tt = 0; tt < LC; ++tt) {
      const float dtv = dp[(size_t)tt * kD];
      const float xv = xp[(size_t)tt * kD];
      const float dtx = dtv * xv;
      float acc = 0.f;
#pragma unroll
      for (int n = 0; n < kN; ++n) {
        s[n] = fmaf(ex2(dtv * AnL[n]), s[n], dtx * Bs[tt * kN + n]);
        acc = fmaf(s[n], Cs[tt * kN + n], acc);
      }
      yp[(size_t)tt * kD] = fmaf(xv, Dv, acc);
    }
  }
}

// ---------------- Fallback: fully sequential (no workspace) ----------------
__global__ __launch_bounds__(256) void ssm_seq(
    const float* __restrict__ x, const float* __restrict__ dt,
    const float* __restrict__ Bin, const float* __restrict__ Cin,
    const float* __restrict__ Alog, const float* __restrict__ Dp,
    float* __restrict__ y) {
  const int gid = blockIdx.x * 256 + threadIdx.x;
  if (gid >= kB * kD) return;
  const int b = gid / kD;
  const int d = gid % kD;

  float AnL[kN];
  const float* al = Alog + (size_t)d * kN;
#pragma unroll
  for (int n = 0; n < kN; ++n) AnL[n] = -__expf(al[n]) * kLog2e;

  float s[kN];
#pragma unroll
  for (int n = 0; n < kN; ++n) s[n] = 0.f;
  const float Dv = Dp[d];

  const float* xp = x + (size_t)b * kL * kD + d;
  const float* dp = dt + (size_t)b * kL * kD + d;
  const float* bp = Bin + (size_t)b * kL * kN;
  const float* cp = Cin + (size_t)b * kL * kN;
  float* yp = y + (size_t)b * kL * kD + d;

  for (int t = 0; t < kL; ++t) {
    const float dtv = dp[(size_t)t * kD];
    const float xv = xp[(size_t)t * kD];
    const float dtx = dtv * xv;
    float acc = 0.f;
#pragma unroll
    for (int n = 0; n < kN; ++n) {
      const float a = ex2(dtv * AnL[n]);
      s[n] = fmaf(a, s[n], dtx * bp[t * kN + n]);
      acc = fmaf(s[n], cp[t * kN + n], acc);
    }
    yp[(size_t)t * kD] = fmaf(xv, Dv, acc);
  }
}

template <int C>
void launch_chunked(const float* x, const float* dtp, const float* Bin,
                    const float* Cin, const float* Alog, const float* Dp,
                    float* y, float* ws, hipStream_t stream) {
  float* WS = ws;                          // C * kBDN
  float* SDT = WS + (size_t)C * kBDN;      // C * kBD
  float* WI = SDT + (size_t)C * kBD;       // C * kBDN
  const int g = C * kB * kNDBLK;
  ssm_phase1<C><<<g, kTPB, 0, stream>>>(x, dtp, Bin, Alog, WS, SDT);
  ssm_phase2<C><<<kBDN / 128, 128, 0, stream>>>(WS, SDT, Alog, WI);
  ssm_phase3<C><<<g, kTPB, 0, stream>>>(x, dtp, Bin, Cin, Alog, Dp, WI, y);
}

}  // namespace

extern "C" void kernel_launch(void* const* d_in, const int* in_sizes, int n_in,
                              void* d_out, int out_size, void* d_ws, size_t ws_size,
                              hipStream_t stream) {
  const float* x    = (const float*)d_in[0];
  const float* dtp  = (const float*)d_in[1];
  const float* Bin  = (const float*)d_in[2];
  const float* Cin  = (const float*)d_in[3];
  const float* Alog = (const float*)d_in[4];
  const float* Dp   = (const float*)d_in[5];
  float* y = (float*)d_out;
  float* ws = (float*)d_ws;

  auto need = [](int C) {
    return (size_t)(2 * C * kBDN + C * kBD) * sizeof(float);
  };

  if (ws_size >= need(128)) {
    launch_chunked<128>(x, dtp, Bin, Cin, Alog, Dp, y, ws, stream);
  } else if (ws_size >= need(64)) {
    launch_chunked<64>(x, dtp, Bin, Cin, Alog, Dp, y, ws, stream);
  } else if (ws_size >= need(16)) {
    launch_chunked<16>(x, dtp, Bin, Cin, Alog, Dp, y, ws, stream);
  } else {
    ssm_seq<<<(kB * kD + 255) / 256, 256, 0, stream>>>(x, dtp, Bin, Cin, Alog,
                                                       Dp, y);
  }
}